// Round 9
// baseline (270.450 us; speedup 1.0000x reference)
//
#include <hip/hip_runtime.h>

typedef __bf16 bf16_t;
using bf16x8 = __attribute__((ext_vector_type(8))) __bf16;
using bf16x4 = __attribute__((ext_vector_type(4))) __bf16;
using f32x4  = __attribute__((ext_vector_type(4))) float;

#define B_   4
#define S_   2048
#define D_   1024
#define H_   16
#define DK_  64
#define SQKV 3072   // QKV buffer row stride (Q|K|V concatenated)

__device__ __forceinline__ void gload_lds16(const void* g, void* l) {
  __builtin_amdgcn_global_load_lds((const __attribute__((address_space(1))) void*)g,
                                   (__attribute__((address_space(3))) void*)l, 16, 0, 0);
}

__device__ __forceinline__ float fast_exp2(float x) {
#if __has_builtin(__builtin_amdgcn_exp2f)
  return __builtin_amdgcn_exp2f(x);
#else
  return __expf(x * 0.69314718f);
#endif
}

// ---------------- fp32 -> bf16 cast (vectorized, optional scale) ----------------
__global__ void cast_f32_to_bf16(const float* __restrict__ in, bf16_t* __restrict__ out,
                                 int n4, float scale) {
  int i = blockIdx.x * 256 + threadIdx.x;
  if (i >= n4) return;
  float4 v = reinterpret_cast<const float4*>(in)[i];
  bf16x4 o;
  o[0] = (bf16_t)(v.x * scale); o[1] = (bf16_t)(v.y * scale);
  o[2] = (bf16_t)(v.z * scale); o[3] = (bf16_t)(v.w * scale);
  reinterpret_cast<bf16x4*>(out)[i] = o;
}

// ---------------- C[M,N] = A[M,K] * B[N,K]^T  (bf16 in, OutT out) ----------------
template <typename OutT>
__global__ void gemm_bt(const bf16_t* __restrict__ A, const bf16_t* __restrict__ Bm,
                        OutT* __restrict__ C, int M, int N, int K) {
  __shared__ alignas(16) char As[16384];
  __shared__ alignas(16) char Bs[16384];
  const int tid  = threadIdx.x;
  const int wid  = tid >> 6, lane = tid & 63;
  const int g    = lane >> 4, l15 = lane & 15;

  int nwg = gridDim.x * gridDim.y;
  int bid = blockIdx.y * gridDim.x + blockIdx.x;
  int sb  = ((nwg & 7) == 0) ? ((bid & 7) * (nwg >> 3) + (bid >> 3)) : bid;
  int bx  = sb % gridDim.x, by = sb / gridDim.x;

  const long row0 = (long)by * 128, col0 = (long)bx * 128;
  const int wr = (wid >> 1) * 64, wc = (wid & 1) * 64;
  f32x4 acc[4][4] = {};

  for (int k0 = 0; k0 < K; k0 += 64) {
    __syncthreads();
#pragma unroll
    for (int i = 0; i < 4; ++i) {
      int L = i * 256 + tid;
      int r = L >> 3, s = L & 7;
      int sc = s ^ (r & 7);
      const bf16_t* ga = A  + (row0 + r) * (long)K + k0 + sc * 8;
      const bf16_t* gb = Bm + (col0 + r) * (long)K + k0 + sc * 8;
      gload_lds16(ga, As + (i * 256 + wid * 64) * 16);
      gload_lds16(gb, Bs + (i * 256 + wid * 64) * 16);
    }
    __syncthreads();
#pragma unroll
    for (int kk = 0; kk < 2; ++kk) {
      bf16x8 af[4], bfr[4];
#pragma unroll
      for (int m = 0; m < 4; ++m) {
        int r = wr + m * 16 + l15;
        int s = (kk * 4 + g) ^ (r & 7);
        af[m] = *reinterpret_cast<const bf16x8*>(As + r * 128 + s * 16);
      }
#pragma unroll
      for (int n = 0; n < 4; ++n) {
        int r = wc + n * 16 + l15;
        int s = (kk * 4 + g) ^ (r & 7);
        bfr[n] = *reinterpret_cast<const bf16x8*>(Bs + r * 128 + s * 16);
      }
#pragma unroll
      for (int m = 0; m < 4; ++m)
#pragma unroll
        for (int n = 0; n < 4; ++n)
          acc[m][n] = __builtin_amdgcn_mfma_f32_16x16x32_bf16(af[m], bfr[n], acc[m][n], 0, 0, 0);
    }
  }
#pragma unroll
  for (int m = 0; m < 4; ++m)
#pragma unroll
    for (int n = 0; n < 4; ++n)
#pragma unroll
      for (int j = 0; j < 4; ++j) {
        long r = row0 + wr + m * 16 + g * 4 + j;
        long c = col0 + wc + n * 16 + l15;
        C[r * (long)N + c] = (OutT)acc[m][n][j];
      }
}

// ---------------- V transpose+permute: QKV V-part -> VT[(b*16+h)*64+d][pos] ------
// pos(kv) = (kv>>5)*32 + ((kv>>2)&3)*8 + ((kv>>4)&1)*4 + (kv&3)
// (inverse: kv(p) = (p>>5)*32 + ((p>>2)&1)*16 + ((p>>3)&3)*4 + (p&3))
// so each lane's PV B-fragment (P^T) is its own exp'd registers (no cross-lane).
__global__ void vtrans_kernel(const bf16_t* __restrict__ qkv, bf16_t* __restrict__ VT) {
  __shared__ bf16_t t[64 * 65];
  const int tid = threadIdx.x;
  const int s0 = blockIdx.x * 64;
  const int bh = blockIdx.y, b = bh >> 4, h = bh & 15;
  {
    int sl = tid >> 2, dc = tid & 3;
    const bf16_t* src = qkv + ((long)(b * S_ + s0 + sl)) * SQKV + 2 * D_ + h * DK_ + dc * 16;
    bf16x8 v0 = *reinterpret_cast<const bf16x8*>(src);
    bf16x8 v1 = *reinterpret_cast<const bf16x8*>(src + 8);
#pragma unroll
    for (int e = 0; e < 8; ++e) t[sl * 65 + dc * 16 + e] = v0[e];
#pragma unroll
    for (int e = 0; e < 8; ++e) t[sl * 65 + dc * 16 + 8 + e] = v1[e];
  }
  __syncthreads();
  {
    int d = tid >> 2, sc = tid & 3;
    bf16x8 o0, o1;
#pragma unroll
    for (int e = 0; e < 8; ++e) {
      int p  = sc * 16 + e;
      int kv = ((p >> 5) << 5) + (((p >> 2) & 1) << 4) + (((p >> 3) & 3) << 2) + (p & 3);
      o0[e] = t[kv * 65 + d];
    }
#pragma unroll
    for (int e = 0; e < 8; ++e) {
      int p  = sc * 16 + 8 + e;
      int kv = ((p >> 5) << 5) + (((p >> 2) & 1) << 4) + (((p >> 3) & 3) << 2) + (p & 3);
      o1[e] = t[kv * 65 + d];
    }
    bf16_t* dst = VT + ((long)(bh * 64 + d)) * S_ + s0 + sc * 16;
    *reinterpret_cast<bf16x8*>(dst) = o0;
    *reinterpret_cast<bf16x8*>(dst + 8) = o1;
  }
}

// ---------------- flash attention (causal), bf16 MFMA, swapped operands ---------
// 128 q-rows per block (4 waves x 2 subtiles of 16 q), KVBLK=64.
// K/V fragments read from LDS ONCE feed TWO MFMAs (one per q-subtile) -> LDS
// bytes per unit work halved vs 64-q blocks. S^T = mfma(K,Q), O^T = mfma(V^T,P^T),
// P stays in registers (kv-axis permutation pre-applied to VT).
__global__ __launch_bounds__(256, 4)
void attn_kernel(const bf16_t* __restrict__ qkv, const bf16_t* __restrict__ VT,
                 bf16_t* __restrict__ Ob) {
  __shared__ alignas(16) char ldsK[2][8192];   // [64 kv][64 d], swizzled
  __shared__ alignas(16) char ldsV[2][8192];   // [64 d][64 pos], swizzled
  const int tid = threadIdx.x;
  const int w   = tid >> 6, lane = tid & 63;
  const int g   = lane >> 4, l15 = lane & 15;

  int bid = blockIdx.y * 16 + blockIdx.x;      // 1024 blocks
  int sb  = (bid & 7) * 128 + (bid >> 3);      // XCD-bijective (1024 % 8 == 0)
  const int qt = 15 - (sb & 15);               // longest-first
  const int bh = sb >> 4;
  const int b  = bh >> 4, h = bh & 15;
  const long rowbase = (long)b * S_;

  bf16x8 qf0[2], qf1[2];
  {
    const bf16_t* qp0 = qkv + (rowbase + qt * 128 + w * 16 + l15) * SQKV + h * DK_ + g * 8;
    qf0[0] = *reinterpret_cast<const bf16x8*>(qp0);
    qf0[1] = *reinterpret_cast<const bf16x8*>(qp0 + 32);
    const bf16_t* qp1 = qp0 + 64 * SQKV;
    qf1[0] = *reinterpret_cast<const bf16x8*>(qp1);
    qf1[1] = *reinterpret_cast<const bf16x8*>(qp1 + 32);
  }
  float m0 = -1e30f, m1 = -1e30f, s0 = 0.f, s1 = 0.f;
  f32x4 o0[4] = {}, o1[4] = {};                // O^T[d = dc*16+g*4+j][q = l15]

  const bf16_t* kbase = qkv + rowbase * SQKV + D_ + h * DK_;
  const bf16_t* vbase = VT + (long)bh * 64 * S_;

  auto stageK = [&](int kvt, int buf) {
#pragma unroll
    for (int i = 0; i < 2; ++i) {
      int L = i * 256 + tid;
      int r = L >> 3, s = L & 7;
      int sc = s ^ (r & 7);
      gload_lds16(kbase + (long)(kvt * 64 + r) * SQKV + sc * 8,
                  ldsK[buf] + L * 16);
    }
  };
  auto stageV = [&](int kvt, int buf) {
#pragma unroll
    for (int i = 0; i < 2; ++i) {
      int L = i * 256 + tid;
      int r = L >> 3, s = L & 7;    // r = d row
      int sc = s ^ (r & 7);
      gload_lds16(vbase + (long)r * S_ + kvt * 64 + sc * 8,
                  ldsV[buf] + L * 16);
    }
  };

  const int last = 2 * qt + 1;                 // kv tiles 0..last
  stageK(0, 0); stageV(0, 0);                  // 4 VMEM ops in flight

  const int qlocal = w * 16 + l15;             // tile-local diag comparison row
  const int gj = g * 4;

  for (int kvt = 0; kvt <= last; ++kvt) {
    const int cur = kvt & 1;
    // own tile-kvt loads landed (issued a full compute-phase ago)
    asm volatile("s_waitcnt vmcnt(0)" ::: "memory");
    // rendezvous after the wait: all waves' tile-kvt in LDS; buf[cur^1] free
    __builtin_amdgcn_s_barrier();
    if (kvt < last) { stageK(kvt + 1, cur ^ 1); stageV(kvt + 1, cur ^ 1); }

    // ---- S^T = K Q^T for both subtiles (kf read once, used twice) ----
    f32x4 sv0[4], sv1[4];
    __builtin_amdgcn_s_setprio(1);
#pragma unroll
    for (int c = 0; c < 4; ++c) {
      f32x4 a0 = {}, a1 = {};
#pragma unroll
      for (int kk = 0; kk < 2; ++kk) {
        int r = c * 16 + l15;
        int s = (kk * 4 + g) ^ (l15 & 7);
        bf16x8 kf = *reinterpret_cast<const bf16x8*>(ldsK[cur] + r * 128 + s * 16);
        a0 = __builtin_amdgcn_mfma_f32_16x16x32_bf16(kf, qf0[kk], a0, 0, 0, 0);
        a1 = __builtin_amdgcn_mfma_f32_16x16x32_bf16(kf, qf1[kk], a1, 0, 0, 0);
      }
      sv0[c] = a0; sv1[c] = a1;
    }
    __builtin_amdgcn_s_setprio(0);

    // ---- causal masking (uniform branches; kv tile 2qt+1 kills subtile 0) ----
    if (kvt == 2 * qt) {
#pragma unroll
      for (int c = 0; c < 4; ++c)
#pragma unroll
        for (int j = 0; j < 4; ++j)
          if ((c * 16 + gj + j) > qlocal) sv0[c][j] = -1e30f;
    } else if (kvt == last) {
#pragma unroll
      for (int c = 0; c < 4; ++c)
#pragma unroll
        for (int j = 0; j < 4; ++j) {
          sv0[c][j] = -1e30f;
          if ((c * 16 + gj + j) > qlocal) sv1[c][j] = -1e30f;
        }
    }

    // ---- defer-max online softmax (log2 domain, q lane-local) ----
    float mx0 = sv0[0][0], mx1 = sv1[0][0];
#pragma unroll
    for (int c = 0; c < 4; ++c)
#pragma unroll
      for (int j = 0; j < 4; ++j) {
        mx0 = fmaxf(mx0, sv0[c][j]);
        mx1 = fmaxf(mx1, sv1[c][j]);
      }
    if (__any(mx0 > m0 + 8.0f)) {
      float mx = fmaxf(mx0, __shfl_xor(mx0, 16));
      mx = fmaxf(mx, __shfl_xor(mx, 32));
      float mn = fmaxf(m0, mx);
      float al = fast_exp2(m0 - mn);
      m0 = mn; s0 *= al;
#pragma unroll
      for (int dc = 0; dc < 4; ++dc)
#pragma unroll
        for (int j = 0; j < 4; ++j) o0[dc][j] *= al;
    }
    if (__any(mx1 > m1 + 8.0f)) {
      float mx = fmaxf(mx1, __shfl_xor(mx1, 16));
      mx = fmaxf(mx, __shfl_xor(mx, 32));
      float mn = fmaxf(m1, mx);
      float al = fast_exp2(m1 - mn);
      m1 = mn; s1 *= al;
#pragma unroll
      for (int dc = 0; dc < 4; ++dc)
#pragma unroll
        for (int j = 0; j < 4; ++j) o1[dc][j] *= al;
    }

    // ---- P^T = exp2(S^T - m) in-register -> PV B-frags directly ----
    bf16x8 pb0[2], pb1[2];
#pragma unroll
    for (int ks = 0; ks < 2; ++ks)
#pragma unroll
      for (int half = 0; half < 2; ++half) {
        int c = ks * 2 + half;
#pragma unroll
        for (int j = 0; j < 4; ++j) {
          float p0 = fast_exp2(sv0[c][j] - m0);
          float p1 = fast_exp2(sv1[c][j] - m1);
          s0 += p0; s1 += p1;
          pb0[ks][half * 4 + j] = (bf16_t)p0;
          pb1[ks][half * 4 + j] = (bf16_t)p1;
        }
      }

    // ---- O^T += V^T P^T (vf read once, used twice) ----
    __builtin_amdgcn_s_setprio(1);
#pragma unroll
    for (int ks = 0; ks < 2; ++ks)
#pragma unroll
      for (int dc = 0; dc < 4; ++dc) {
        int r = dc * 16 + l15;
        int s = (ks * 4 + g) ^ (l15 & 7);
        bf16x8 vf = *reinterpret_cast<const bf16x8*>(ldsV[cur] + r * 128 + s * 16);
        o0[dc] = __builtin_amdgcn_mfma_f32_16x16x32_bf16(vf, pb0[ks], o0[dc], 0, 0, 0);
        o1[dc] = __builtin_amdgcn_mfma_f32_16x16x32_bf16(vf, pb1[ks], o1[dc], 0, 0, 0);
      }
    __builtin_amdgcn_s_setprio(0);
  }

  // final: reduce sums over g-lanes, normalize, write both subtiles
  s0 += __shfl_xor(s0, 16); s0 += __shfl_xor(s0, 32);
  s1 += __shfl_xor(s1, 16); s1 += __shfl_xor(s1, 32);
  float inv0 = 1.0f / s0, inv1 = 1.0f / s1;
  long r0 = rowbase + qt * 128 + w * 16 + l15;
#pragma unroll
  for (int dc = 0; dc < 4; ++dc) {
    bf16x4 oa, ob;
#pragma unroll
    for (int j = 0; j < 4; ++j) {
      oa[j] = (bf16_t)(o0[dc][j] * inv0);
      ob[j] = (bf16_t)(o1[dc][j] * inv1);
    }
    *reinterpret_cast<bf16x4*>(&Ob[r0 * D_ + h * DK_ + dc * 16 + gj]) = oa;
    *reinterpret_cast<bf16x4*>(&Ob[(r0 + 64) * D_ + h * DK_ + dc * 16 + gj]) = ob;
  }
}

// ---------------- launch ----------------
extern "C" void kernel_launch(void* const* d_in, const int* in_sizes, int n_in,
                              void* d_out, int out_size, void* d_ws, size_t ws_size,
                              hipStream_t stream) {
  const float* x  = (const float*)d_in[0];
  const float* Wq = (const float*)d_in[1];
  const float* Wk = (const float*)d_in[2];
  const float* Wv = (const float*)d_in[3];
  const float* Wo = (const float*)d_in[4];
  float* out = (float*)d_out;

  char* ws = (char*)d_ws;
  bf16_t* xb  = (bf16_t*)(ws);                    // [8192,1024]  (reused as VT later)
  bf16_t* Wc  = (bf16_t*)(ws + 16777216);         // [3072,1024]
  bf16_t* Wob = (bf16_t*)(ws + 23068672);         // [1024,1024]
  bf16_t* QKV = (bf16_t*)(ws + 25165824);         // [8192,3072]
  bf16_t* Ob  = (bf16_t*)(ws + 75497472);         // [8192,1024]
  bf16_t* VT  = xb;                               // [4096,2048] overlays dead xb

  const float QSCALE = 0.18033688f;               // 0.125 * log2(e)

  cast_f32_to_bf16<<<8192, 256, 0, stream>>>(x,  xb,            2097152, 1.0f);
  cast_f32_to_bf16<<<1024, 256, 0, stream>>>(Wq, Wc,             262144, QSCALE);
  cast_f32_to_bf16<<<1024, 256, 0, stream>>>(Wk, Wc + 1048576,   262144, 1.0f);
  cast_f32_to_bf16<<<1024, 256, 0, stream>>>(Wv, Wc + 2097152,   262144, 1.0f);
  cast_f32_to_bf16<<<1024, 256, 0, stream>>>(Wo, Wob,            262144, 1.0f);

  gemm_bt<bf16_t><<<dim3(24, 64), 256, 0, stream>>>(xb, Wc, QKV, 8192, 3072, 1024);
  vtrans_kernel<<<dim3(32, 64), 256, 0, stream>>>(QKV, VT);       // xb dead now
  attn_kernel<<<dim3(16, 64), 256, 0, stream>>>(QKV, VT, Ob);
  gemm_bt<float><<<dim3(8, 64), 256, 0, stream>>>(Ob, Wob, out, 8192, 1024, 1024);
}